// Round 8
// baseline (565.565 us; speedup 1.0000x reference)
//
#include <hip/hip_runtime.h>
#include <math.h>

#define NK 512                      // N_EMB
#define NPTS (32*64*64)             // 131072 points
#define NELEM (32*64*64*64)         // 8388608 elements of z

// flat d_out offsets (return order: loss, z_q, perplexity, encodings, codebook)
#define OFF_LOSS 0
#define OFF_ZQ   1
#define OFF_PERP (1 + NELEM)
#define OFF_ENC  (2 + NELEM)
#define OFF_CB   (2 + NELEM + (size_t)NPTS * NK)

// ws layout: [0,2048) hist int[512] | [2048,2056) lossAcc double |
//            [4096, +128KB) wTT f32[64 chunks][64 d][8 codes] | then bnd f32[512]

// ---- prep: wTT[(c*64+d)*8+j] = w[c*8+j][d]; bnd[k] = sum_d w[k][d]^2 (sequential d) ----
__global__ __launch_bounds__(256) void vq_prep(const float* __restrict__ wg,
                                               float* __restrict__ wTT,
                                               float* __restrict__ bnd) {
    __shared__ float tl[64 * 65];
    const int t = threadIdx.x;
    const int kbase = blockIdx.x * 64;          // 8 blocks x 64 codes
    #pragma unroll
    for (int it = 0; it < 16; ++it) {
        int i = it * 256 + t;
        int k = i >> 6, d = i & 63;
        tl[k * 65 + d] = wg[(size_t)(kbase + k) * 64 + d];
    }
    __syncthreads();
    #pragma unroll
    for (int it = 0; it < 16; ++it) {
        int i = it * 256 + t;
        int kk = i & 63, d = i >> 6;
        int k = kbase + kk;
        wTT[(size_t)((k >> 3) * 64 + d) * 8 + (k & 7)] = tl[kk * 65 + d];
    }
    if (t < 64) {
        float s = 0.f;
        #pragma unroll 4
        for (int d = 0; d < 64; ++d) {
            float v = tl[t * 65 + d];
            s = __fadd_rn(s, __fmul_rn(v, v));
        }
        bnd[kbase + t] = s;
    }
}

// ---- macros keep every z access a named SSA value (no alloca -> no scratch) ----
#define LOADZ(Z, d0) \
    Z.x = zg[base + (size_t)((d0)+0) * 4096 + lane]; \
    Z.y = zg[base + (size_t)((d0)+1) * 4096 + lane]; \
    Z.z = zg[base + (size_t)((d0)+2) * 4096 + lane]; \
    Z.w = zg[base + (size_t)((d0)+3) * 4096 + lane];

#define NRM4(Z) \
    a = __fadd_rn(a, __fmul_rn(Z.x, Z.x)); \
    a = __fadd_rn(a, __fmul_rn(Z.y, Z.y)); \
    a = __fadd_rn(a, __fmul_rn(Z.z, Z.z)); \
    a = __fadd_rn(a, __fmul_rn(Z.w, Z.w));

#define FMA8(zv, dd) { \
    const float* wp_ = wrow + (dd) * 8; \
    A0.x = fmaf(zv, wp_[0], A0.x); A0.y = fmaf(zv, wp_[1], A0.y); \
    A0.z = fmaf(zv, wp_[2], A0.z); A0.w = fmaf(zv, wp_[3], A0.w); \
    A1.x = fmaf(zv, wp_[4], A1.x); A1.y = fmaf(zv, wp_[5], A1.y); \
    A1.z = fmaf(zv, wp_[6], A1.z); A1.w = fmaf(zv, wp_[7], A1.w); }

#define FMA4x8(Z, d0) FMA8(Z.x, d0) FMA8(Z.y, (d0)+1) FMA8(Z.z, (d0)+2) FMA8(Z.w, (d0)+3)

#define ARGMIN1(av, bv, j) { \
    float dist_ = __fsub_rn(__fadd_rn(a, bv), 2.0f * av); \
    if (dist_ < best) { best = dist_; bidx = cc * 8 + (j); } }

#define ZQ1(zc, qc, dd) { \
    float df_ = __fsub_rn(qc, zc); \
    lsum = __fadd_rn(lsum, __fmul_rn(df_, df_)); \
    zq[(size_t)(dd) * 4096 + lane] = __fadd_rn(zc, df_); }

#define ZQ4(Z, e) { \
    float4 qv_ = wr4[e]; \
    ZQ1(Z.x, qv_.x, 4*(e)+0) ZQ1(Z.y, qv_.y, 4*(e)+1) \
    ZQ1(Z.z, qv_.z, 4*(e)+2) ZQ1(Z.w, qv_.w, 4*(e)+3) }

// Fused kernel: 512 blocks x 256 threads. wave = one (b,h) row, ALL 512 codes.
// lane = point. z in 16 named float4 SSA values (cannot hit scratch).
// Codes via scalar pipe (wave-uniform wTT reads -> s_load + v_fmac v,s,v).
// Inner loop: zero LDS / zero per-lane vector memory. No barriers.
__global__ __launch_bounds__(256, 2) void vq_fused(const float* __restrict__ zg,
                                                   const float* __restrict__ wg,
                                                   const float* __restrict__ wTT,
                                                   const float* __restrict__ bndg,
                                                   float* __restrict__ out,
                                                   int* __restrict__ hist,
                                                   double* __restrict__ lossAcc) {
    const int t = threadIdx.x;
    const int wave = t >> 6;
    const int lane = t & 63;
    const int r = blockIdx.x * 4 + wave;       // 2048 rows = (b,h)
    const int b = r >> 6;
    const int h = r & 63;
    const size_t base = (size_t)b * 262144 + (size_t)h * 64;   // + d*4096 + lane

    // ---- z row into named registers: lane p gets z[b, d, h, p] ----
    float4 Z0, Z1, Z2, Z3, Z4, Z5, Z6, Z7, Z8, Z9, Z10, Z11, Z12, Z13, Z14, Z15;
    LOADZ(Z0, 0)   LOADZ(Z1, 4)   LOADZ(Z2, 8)   LOADZ(Z3, 12)
    LOADZ(Z4, 16)  LOADZ(Z5, 20)  LOADZ(Z6, 24)  LOADZ(Z7, 28)
    LOADZ(Z8, 32)  LOADZ(Z9, 36)  LOADZ(Z10, 40) LOADZ(Z11, 44)
    LOADZ(Z12, 48) LOADZ(Z13, 52) LOADZ(Z14, 56) LOADZ(Z15, 60)

    // ---- a = sum_d z^2 (sequential d, mul+add — matches reference) ----
    float a = 0.f;
    NRM4(Z0)  NRM4(Z1)  NRM4(Z2)  NRM4(Z3)
    NRM4(Z4)  NRM4(Z5)  NRM4(Z6)  NRM4(Z7)
    NRM4(Z8)  NRM4(Z9)  NRM4(Z10) NRM4(Z11)
    NRM4(Z12) NRM4(Z13) NRM4(Z14) NRM4(Z15)

    float best = INFINITY;
    int bidx = 0;

    #pragma unroll 1
    for (int cc = 0; cc < 64; ++cc) {
        const float* wrow = wTT + cc * 512;     // wave-uniform -> scalar loads
        float4 A0 = make_float4(0.f, 0.f, 0.f, 0.f);
        float4 A1 = make_float4(0.f, 0.f, 0.f, 0.f);

        FMA4x8(Z0, 0)   FMA4x8(Z1, 4)   FMA4x8(Z2, 8)   FMA4x8(Z3, 12)
        FMA4x8(Z4, 16)  FMA4x8(Z5, 20)  FMA4x8(Z6, 24)  FMA4x8(Z7, 28)
        FMA4x8(Z8, 32)  FMA4x8(Z9, 36)  FMA4x8(Z10, 40) FMA4x8(Z11, 44)
        FMA4x8(Z12, 48) FMA4x8(Z13, 52) FMA4x8(Z14, 56) FMA4x8(Z15, 60)

        // dist = fl(fl(a+b) - 2*dot); ascending k + strict < = first-index
        const float4 B0 = *(const float4*)(bndg + cc * 8);
        const float4 B1 = *(const float4*)(bndg + cc * 8 + 4);
        ARGMIN1(A0.x, B0.x, 0) ARGMIN1(A0.y, B0.y, 1)
        ARGMIN1(A0.z, B0.z, 2) ARGMIN1(A0.w, B0.w, 3)
        ARGMIN1(A1.x, B1.x, 4) ARGMIN1(A1.y, B1.y, 5)
        ARGMIN1(A1.z, B1.z, 6) ARGMIN1(A1.w, B1.w, 7)
    }

    // ---- codebook + histogram ----
    out[OFF_CB + (size_t)r * 64 + lane] = (float)bidx;
    atomicAdd(&hist[bidx], 1);

    // ---- z_q (straight-through) + loss partial ----
    float lsum = 0.f;
    {
        const float4* wr4 = (const float4*)(wg + (size_t)bidx * 64);  // per-lane gather
        float* zq = out + OFF_ZQ + base;
        ZQ4(Z0, 0)   ZQ4(Z1, 1)   ZQ4(Z2, 2)   ZQ4(Z3, 3)
        ZQ4(Z4, 4)   ZQ4(Z5, 5)   ZQ4(Z6, 6)   ZQ4(Z7, 7)
        ZQ4(Z8, 8)   ZQ4(Z9, 9)   ZQ4(Z10, 10) ZQ4(Z11, 11)
        ZQ4(Z12, 12) ZQ4(Z13, 13) ZQ4(Z14, 14) ZQ4(Z15, 15)
    }
    #pragma unroll
    for (int off = 32; off > 0; off >>= 1)
        lsum += __shfl_down(lsum, off);
    if (lane == 0)
        atomicAdd(lossAcc, (double)lsum);

    // ---- encodings: 64 one-hot rows, dense coalesced float4 (Z regs dead here) ----
    {
        float* encb = out + OFF_ENC + ((size_t)r * 64) * 512;
        const int e0 = lane * 4;          // floats [e0,e0+4) and [256+e0, 256+e0+4)
        #pragma unroll 4
        for (int p = 0; p < 64; ++p) {
            int idx = __shfl(bidx, p);    // point p's winner, broadcast in-wave
            float* erow = encb + (size_t)p * 512;
            float4 A, B;
            A.x = (e0 + 0 == idx) ? 1.f : 0.f;
            A.y = (e0 + 1 == idx) ? 1.f : 0.f;
            A.z = (e0 + 2 == idx) ? 1.f : 0.f;
            A.w = (e0 + 3 == idx) ? 1.f : 0.f;
            B.x = (e0 + 256 == idx) ? 1.f : 0.f;
            B.y = (e0 + 257 == idx) ? 1.f : 0.f;
            B.z = (e0 + 258 == idx) ? 1.f : 0.f;
            B.w = (e0 + 259 == idx) ? 1.f : 0.f;
            *(float4*)(erow + e0) = A;
            *(float4*)(erow + 256 + e0) = B;
        }
    }
}

__global__ __launch_bounds__(512) void vq_finalize(const int* __restrict__ hist,
                                                   const double* __restrict__ lossAcc,
                                                   float* __restrict__ out) {
    __shared__ float sh[512];
    const int t = threadIdx.x;
    float p = (float)hist[t] / (float)NPTS;   // exact: /2^17
    sh[t] = __fmul_rn(p, logf(__fadd_rn(p, 1e-10f)));
    __syncthreads();
    for (int s = 256; s > 0; s >>= 1) {
        if (t < s) sh[t] += sh[t + s];
        __syncthreads();
    }
    if (t == 0) {
        float m = (float)(*lossAcc / (double)NELEM);
        out[OFF_LOSS] = __fadd_rn(m, __fmul_rn(0.25f, m));
        out[OFF_PERP] = expf(-sh[0]);
    }
}

extern "C" void kernel_launch(void* const* d_in, const int* in_sizes, int n_in,
                              void* d_out, int out_size, void* d_ws, size_t ws_size,
                              hipStream_t stream) {
    const float* z = (const float*)d_in[0];
    const float* w = (const float*)d_in[1];
    float* out = (float*)d_out;
    int* hist = (int*)d_ws;
    double* lossAcc = (double*)((char*)d_ws + 2048);
    float* wTT = (float*)((char*)d_ws + 4096);
    float* bnd = wTT + 64 * 512;

    (void)hipMemsetAsync(d_ws, 0, 4096, stream);
    vq_prep<<<8, 256, 0, stream>>>(w, wTT, bnd);
    vq_fused<<<512, 256, 0, stream>>>(z, w, wTT, bnd, out, hist, lossAcc);
    vq_finalize<<<1, 512, 0, stream>>>(hist, lossAcc, out);
}